// Round 1
// baseline (474.254 us; speedup 1.0000x reference)
//
#include <hip/hip_runtime.h>

// GetCostVolume: out[b, 0:C,  d,h,w] = x[b,c,h,w]                  (broadcast over d)
//                out[b, C:2C, d,h,w] = bilinear_zeros(y[b,c], ix(d,h,w), iy(h))
// B=1, C=32, H=128, W=256, D=48  (fixed by harness setup_inputs)

namespace {
constexpr int C = 32, D = 48, H = 128, W = 256;
constexpr int HW = H * W;          // 32768
constexpr int DHW = D * H * W;     // 1,572,864
}

__global__ __launch_bounds__(256) void cost_volume_kernel(
    const float* __restrict__ x, const float* __restrict__ y,
    const float* __restrict__ disp, float* __restrict__ out)
{
    const int t = threadIdx.x;
    const int g = t >> 6;                 // 4 waves per block, one (d,h) row each
    const int lane = t & 63;
    const int r = blockIdx.x * 4 + g;     // row index in [0, D*H)
    const int d = r >> 7;                 // H = 128
    const int h = r & 127;
    const int w0 = lane << 2;             // each lane covers 4 consecutive w

    // ---- y-direction interpolation params (uniform within the wave) ----
    const float gy = (float)h / 63.5f - 1.0f;                  // (H-1)/2 = 63.5
    const float iy = ((gy + 1.0f) * 128.0f - 1.0f) * 0.5f;
    const float y0f = floorf(iy);
    const float wy = iy - y0f;
    const int y0i = (int)y0f;
    const int y1i = y0i + 1;
    const float my0 = (y0i >= 0 && y0i < H) ? 1.0f : 0.0f;
    const float my1 = (y1i >= 0 && y1i < H) ? 1.0f : 0.0f;
    const int y0c = min(max(y0i, 0), H - 1);
    const int y1c = min(max(y1i, 0), H - 1);

    // ---- per-w interpolation params (computed once, reused for all C) ----
    const float4 dsp = *(const float4*)(disp + (d * H + h) * W + w0);
    const float dv[4] = {dsp.x, dsp.y, dsp.z, dsp.w};

    int off00[4], off01[4], off10[4], off11[4];
    float w00[4], w01[4], w10[4], w11[4];
#pragma unroll
    for (int j = 0; j < 4; ++j) {
        const float cur_x = (float)(w0 + j) - dv[j];
        const float gx = cur_x / 127.5f - 1.0f;                // (W-1)/2 = 127.5
        const float ix = ((gx + 1.0f) * 256.0f - 1.0f) * 0.5f;
        const float x0f = floorf(ix);
        const float wx = ix - x0f;
        const int x0i = (int)x0f;
        const int x1i = x0i + 1;
        const float mx0 = (x0i >= 0 && x0i < W) ? 1.0f : 0.0f;
        const float mx1 = (x1i >= 0 && x1i < W) ? 1.0f : 0.0f;
        const int x0c = min(max(x0i, 0), W - 1);
        const int x1c = min(max(x1i, 0), W - 1);
        off00[j] = y0c * W + x0c;
        off01[j] = y0c * W + x1c;
        off10[j] = y1c * W + x0c;
        off11[j] = y1c * W + x1c;
        const float omwx = 1.0f - wx;
        const float omwy = 1.0f - wy;
        // fold zeros-padding masks into the weights -> unconditional loads
        w00[j] = omwx * omwy * mx0 * my0;
        w01[j] = wx   * omwy * mx1 * my0;
        w10[j] = omwx * wy   * mx0 * my1;
        w11[j] = wx   * wy   * mx1 * my1;
    }

    const int xoff = h * W + w0;                 // within one x channel
    const int orow = (d * H + h) * W + w0;       // within one out c2-slab
    float* outL = out + orow;                    // c2 = c
    float* outR = out + C * DHW + orow;          // c2 = C + c

#pragma unroll 2
    for (int c = 0; c < C; ++c) {
        const float* __restrict__ yc = y + c * HW;   // uniform base per c -> saddr loads
        float4 v;
        float* vp = (float*)&v;
#pragma unroll
        for (int j = 0; j < 4; ++j) {
            vp[j] = yc[off00[j]] * w00[j] + yc[off01[j]] * w01[j]
                  + yc[off10[j]] * w10[j] + yc[off11[j]] * w11[j];
        }
        const float4 xl = *(const float4*)(x + c * HW + xoff);
        *(float4*)(outL + c * DHW) = xl;
        *(float4*)(outR + c * DHW) = v;
    }
}

extern "C" void kernel_launch(void* const* d_in, const int* in_sizes, int n_in,
                              void* d_out, int out_size, void* d_ws, size_t ws_size,
                              hipStream_t stream) {
    const float* x    = (const float*)d_in[0];
    const float* y    = (const float*)d_in[1];
    const float* disp = (const float*)d_in[2];
    float* out = (float*)d_out;

    // D*H = 6144 rows, 4 rows per block -> 1536 blocks of 256 threads
    cost_volume_kernel<<<dim3(D * H / 4), dim3(256), 0, stream>>>(x, y, disp, out);
}

// Round 2
// 420.535 us; speedup vs baseline: 1.1277x; 1.1277x over previous
//
#include <hip/hip_runtime.h>

// GetCostVolume: out[0, 0:C,  d,h,w] = x[c,h,w]   (broadcast over d)
//                out[0, C:2C, d,h,w] = bilinear_zeros(y[c], ix(d,h,w), iy(h))
// B=1, C=32, H=128, W=256, D=48.
//
// Key structure: iy depends only on h -> for a block at (h, w-tile) ALL 48 d
// gather from the same two y rows, x within [w0-66, w0+65]. Stage those rows
// in LDS channel-contiguous once, then gathers are ds_read_b128 along c.

typedef float v4f __attribute__((ext_vector_type(4)));

namespace {
constexpr int C = 32, D = 48, H = 128, W = 256;
constexpr int HW  = H * W;        // 32768
constexpr int DHW = D * HW;       // 1,572,864
constexpr int TW   = 64;          // w-tile per block
constexpr int SPAN = 132;         // staged x span: [w0-66, w0+65]
constexpr int CP   = 36;          // padded channel stride (16B-aligned, bank-spread)
constexpr int NPAR = D * TW;      // 3072 (d,w) params per block
}

__global__ __launch_bounds__(256, 2) void cost_volume_kernel(
    const float* __restrict__ x, const float* __restrict__ y,
    const float* __restrict__ disp, float* __restrict__ out)
{
    __shared__ __align__(16) float ys[2 * SPAN * CP];   // [row][j][c pad36] = 38016 B
    __shared__ float s_wx[NPAR];                        // 12288 B
    __shared__ int   s_xj[NPAR];                        // 12288 B

    const int t  = threadIdx.x;
    const int bx = blockIdx.x;
    const int h  = bx >> 2;            // 128 h-rows
    const int w0 = (bx & 3) * TW;      // 4 w-tiles
    const int xlo = w0 - 66;

    // ---- phase 0: per-(d,w) params: wx and staged x-index ----
    for (int id = t; id < NPAR; id += 256) {
        const int d = id >> 6, w = id & 63;
        const float dv = disp[d * HW + h * W + w0 + w];
        const float cur_x = (float)(w0 + w) - dv;
        const float gx = cur_x / 127.5f - 1.0f;               // (W-1)/2
        const float ix = ((gx + 1.0f) * 256.0f - 1.0f) * 0.5f;
        const float x0f = floorf(ix);
        s_wx[id] = ix - x0f;
        const int j = (int)x0f - xlo;                         // in [0,130] by construction
        s_xj[id] = min(max(j, 0), SPAN - 2);                  // safety clamp
    }

    // ---- y-row interpolation params (uniform over block) ----
    const float gy  = (float)h / 63.5f - 1.0f;                // (H-1)/2
    const float iy  = ((gy + 1.0f) * 128.0f - 1.0f) * 0.5f;
    const float y0f = floorf(iy);
    const float wy  = iy - y0f;
    const int   y0i = (int)y0f;

    // ---- phase 1: stage 2 y-rows x 32 c x 132 j, zeros for OOB (replaces masks) ----
    {
        const int seg = t >> 2;            // 0..63 : (row, c)
        const int row = seg >> 5;
        const int cc  = seg & 31;
        const int yr  = y0i + row;
        const bool vr = (yr >= 0) && (yr < H);
        const float* ysrc = y + cc * HW + yr * W;
        for (int j = (t & 3); j < SPAN; j += 4) {
            const int xg = xlo + j;
            float v = 0.0f;
            if (vr && xg >= 0 && xg < W) v = ysrc[xg];
            ys[(row * SPAN + j) * CP + cc] = v;
        }
    }
    __syncthreads();

    // ---- phase 2: each thread computes a 4c x 4w tile per d, d-loop step 2 ----
    const int wq = t & 15;                 // 16 w-quads cover 64 w
    const int cq = (t >> 4) & 7;           // 8 c-quads cover 32 c
    const int d0 = t >> 7;                 // 2 d phases
    const int c0 = cq * 4;
    const int wb = wq * 4;

    // left-half (broadcast x) values, loaded once
    v4f xv[4];
#pragma unroll
    for (int cc = 0; cc < 4; ++cc)
        xv[cc] = *(const v4f*)(x + (c0 + cc) * HW + h * W + w0 + wb);

    const float omy = 1.0f - wy;
    float* const outL = out + h * W + w0 + wb;   // + c*DHW + d*HW

    for (int i = 0; i < 24; ++i) {
        const int d = d0 + 2 * i;
        const int pid = d * TW + wb;
        float res[4][4];
#pragma unroll
        for (int k = 0; k < 4; ++k) {
            const float wx = s_wx[pid + k];      // broadcast across cq groups
            const int   j  = s_xj[pid + k];
            const float omx = 1.0f - wx;
            const float w00 = omx * omy, w01 = wx * omy;
            const float w10 = omx * wy,  w11 = wx * wy;
            const float* p0 = ys + j * CP + c0;          // row 0, x0
            const float* p1 = p0 + SPAN * CP;            // row 1
            const v4f v00 = *(const v4f*)p0;
            const v4f v01 = *(const v4f*)(p0 + CP);      // x0+1
            const v4f v10 = *(const v4f*)p1;
            const v4f v11 = *(const v4f*)(p1 + CP);
#pragma unroll
            for (int cc = 0; cc < 4; ++cc)
                res[cc][k] = fmaf(v11[cc], w11, fmaf(v10[cc], w10,
                              fmaf(v01[cc], w01, v00[cc] * w00)));
        }
        float* const ob = outL + d * HW;
#pragma unroll
        for (int cc = 0; cc < 4; ++cc) {
            const v4f r = { res[cc][0], res[cc][1], res[cc][2], res[cc][3] };
            __builtin_nontemporal_store(xv[cc], (v4f*)(ob + (c0 + cc) * DHW));
            __builtin_nontemporal_store(r, (v4f*)(ob + (C + c0 + cc) * DHW));
        }
    }
}

extern "C" void kernel_launch(void* const* d_in, const int* in_sizes, int n_in,
                              void* d_out, int out_size, void* d_ws, size_t ws_size,
                              hipStream_t stream) {
    const float* x    = (const float*)d_in[0];
    const float* y    = (const float*)d_in[1];
    const float* disp = (const float*)d_in[2];
    float* out = (float*)d_out;

    // H * (W/TW) = 128 * 4 = 512 blocks, 256 threads; 2 blocks/CU -> full residency
    cost_volume_kernel<<<dim3(H * (W / TW)), dim3(256), 0, stream>>>(x, y, disp, out);
}